// Round 3
// baseline (1369.472 us; speedup 1.0000x reference)
//
#include <hip/hip_runtime.h>

typedef unsigned short u16;
typedef unsigned int   u32;
typedef __attribute__((ext_vector_type(8)))  __bf16 bf16x8;
typedef __attribute__((ext_vector_type(4)))  float  f32x4;
typedef __attribute__((ext_vector_type(16))) float  f32x16;

__device__ __forceinline__ float bf2f(u16 u) {
    union { u32 i; float f; } v; v.i = ((u32)u) << 16; return v.f;
}
__device__ __forceinline__ u16 f2bf(float f) {
    u32 u = __float_as_uint(f);
    u32 r = (u + 0x7FFFu + ((u >> 16) & 1u)) >> 16;
    return (u16)r;
}

__device__ __forceinline__ void gl16(const u16* g, u16* l) {
    __builtin_amdgcn_global_load_lds(
        (const __attribute__((address_space(1))) unsigned int*)g,
        (__attribute__((address_space(3))) unsigned int*)l, 16, 0, 0);
}

// ---------------------------------------------------------------------------
// Kernel 1: grouped directional conv 5x5, C=32 -> 256, pad=2, no bias.
// x: NCHW f32 (8,32,128,128); out coeffs: NHWC bf16 (8,128,128,256).
// ---------------------------------------------------------------------------
__global__ __launch_bounds__(256) void dir_conv_k(const float* __restrict__ x,
                                                  const float* __restrict__ wd,
                                                  u16* __restrict__ coeffs) {
    int bid = blockIdx.x;
    int cc = bid & 3, y = (bid >> 2) & 127, n = bid >> 9;
    __shared__ float lx[5280];   // [8 c][5 ky][132 xx]
    __shared__ float lw[1600];   // [25 tap][64 oc_local]
    int t = threadIdx.x;
    for (int i = t; i < 1600; i += 256) {
        int ol = i / 25, tap = i - ol * 25;
        lw[tap * 64 + ol] = wd[(cc * 64 + ol) * 25 + tap];
    }
    for (int i = t; i < 5280; i += 256) {
        int c = i / 660, rem = i - c * 660;
        int ky = rem / 132, xx = rem - ky * 132;
        int gy = y - 2 + ky, gx = xx - 2;
        float v = 0.f;
        if (gy >= 0 && gy < 128 && gx >= 0 && gx < 128)
            v = x[(((n * 32 + cc * 8 + c) * 128 + gy) << 7) + gx];
        lx[i] = v;
    }
    __syncthreads();
    int px = t >> 1, oh = t & 1;
    float acc[4][8];
#pragma unroll
    for (int j = 0; j < 4; ++j)
#pragma unroll
        for (int d = 0; d < 8; ++d) acc[j][d] = 0.f;
#pragma unroll
    for (int j = 0; j < 4; ++j) {
        int cl = oh * 4 + j;
        const float* lxc = &lx[cl * 660];
#pragma unroll
        for (int ky = 0; ky < 5; ++ky)
#pragma unroll
            for (int kx = 0; kx < 5; ++kx) {
                float xv = lxc[ky * 132 + px + kx];
                const float* w8 = &lw[(ky * 5 + kx) * 64 + cl * 8];
#pragma unroll
                for (int d = 0; d < 8; ++d) acc[j][d] += xv * w8[d];
            }
    }
    long base = ((long)((n * 128 + y) * 128 + px)) * 256 + cc * 64 + oh * 32;
#pragma unroll
    for (int j = 0; j < 4; ++j) {
        uint4 o;
        o.x = (u32)f2bf(acc[j][0]) | ((u32)f2bf(acc[j][1]) << 16);
        o.y = (u32)f2bf(acc[j][2]) | ((u32)f2bf(acc[j][3]) << 16);
        o.z = (u32)f2bf(acc[j][4]) | ((u32)f2bf(acc[j][5]) << 16);
        o.w = (u32)f2bf(acc[j][6]) | ((u32)f2bf(acc[j][7]) << 16);
        *(uint4*)(coeffs + base + j * 8) = o;
    }
}

// ---------------------------------------------------------------------------
// Repack conv weights OIHW f32 -> 32x32x16 B-fragment-order bf16:
// wp[((((tap*KC+kc)*2+s)*OC+oc)*2+h)*8 + j] = w[oc][kc*32+s*16+h*8+j][tap]
// ---------------------------------------------------------------------------
__global__ __launch_bounds__(256) void repack_w_k(const float* __restrict__ w,
                                                  u16* __restrict__ wp,
                                                  int OC, int IC, int total) {
    int f = blockIdx.x * 256 + threadIdx.x;
    if (f >= total) return;
    int KC = IC >> 5;
    int j  = f & 7;
    int h  = (f >> 3) & 1;
    int g  = f >> 4;           // ((tap*KC+kc)*2+s)*OC + oc
    int oc = g % OC; g /= OC;
    int s  = g & 1;  g >>= 1;  // tap*KC + kc
    int kc = g % KC;
    int tap = g / KC;
    int ic = kc * 32 + s * 16 + h * 8 + j;
    wp[f] = f2bf(w[(oc * IC + ic) * 9 + tap]);
}

// ---------------------------------------------------------------------------
// 3x3 conv, NHWC bf16 in/out, implicit GEMM with mfma_f32_32x32x16_bf16.
// 4 waves; wave tile 64px x 128oc (2 mf x 4 nf frags of 32x32).
// Block tile: (WM*64)px x (WN*128)oc.  A staged via global_load_lds into
// LDS [4 icq][3 dy][W x] 16B units (consecutive-unit fragment reads).
// B read from global in exact fragment order (L2-resident).
// ---------------------------------------------------------------------------
template<int IC, int OC, int WM, int WN>
__global__ __launch_bounds__(256) void conv3_k(const u16* __restrict__ in,
                                               const u16* __restrict__ wp,
                                               const float* __restrict__ bias,
                                               const u16* __restrict__ zp,
                                               u16* __restrict__ outp) {
    constexpr int KC = IC / 32;
    constexpr int W  = WM * 64 + 2;
    constexpr int TU = 12 * W;          // total 16B staging units
    constexpr int NFULL = TU / 256;
    constexpr int REM   = TU % 256;
    __shared__ u16 lA[TU * 8];

    int bx = blockIdx.x;
    int n, y, x0;
    if (WM == 1) { x0 = (bx & 1) << 6; y = (bx >> 1) & 127; n = bx >> 8; }
    else         { x0 = 0;             y = bx & 127;        n = bx >> 7; }
    int t = threadIdx.x, lane = t & 63, wv = t >> 6;
    int wm = (WM == 1) ? 0 : (wv & 1);
    int wn = (WM == 1) ? wv : (wv >> 1);
    int lm = lane & 31, h = lane >> 5;
    int ocw = wn * 128;

    // ---- precompute per-lane staging source pointers (kc-invariant part) ----
    const u16* ptrs[NFULL + 1];
#pragma unroll
    for (int i = 0; i <= NFULL; ++i) {
        int u = (i == NFULL) ? (NFULL * 256 + lane) : (i * 256 + wv * 64 + lane);
        int icq = u / (3 * W);
        int r2  = u - icq * (3 * W);
        int dy  = r2 / W;
        int xx  = r2 - dy * W;
        int gy = y - 1 + dy, gx = x0 - 1 + xx;
        bool ok = ((unsigned)gy < 128u) && ((unsigned)gx < 128u);
        ptrs[i] = ok ? (in + (long)((n * 128 + gy) * 128 + gx) * IC + icq * 8)
                     : zp;
    }

    f32x16 acc[2][4];
#pragma unroll
    for (int mf = 0; mf < 2; ++mf)
#pragma unroll
        for (int nf = 0; nf < 4; ++nf)
#pragma unroll
            for (int r = 0; r < 16; ++r) acc[mf][nf][r] = 0.f;

    for (int kc = 0; kc < KC; ++kc) {
        __syncthreads();                       // previous compute done
#pragma unroll
        for (int i = 0; i < NFULL; ++i)
            gl16(ptrs[i] + kc * 32, lA + (i * 256 + wv * 64) * 8);
        if (REM && wv == 0 && lane < REM)
            gl16(ptrs[NFULL] + kc * 32, lA + NFULL * 256 * 8);
        __syncthreads();                       // staging complete (vmcnt drained)

#pragma unroll
        for (int dy = 0; dy < 3; ++dy)
#pragma unroll
            for (int dx = 0; dx < 3; ++dx)
#pragma unroll
                for (int s = 0; s < 2; ++s) {
                    int tap = dy * 3 + dx;
                    long wb = (((long)(tap * KC + kc) * 2 + s) * OC
                               + ocw + lm) * 16 + h * 8;
                    bf16x8 b0 = *(const bf16x8*)(wp + wb);
                    bf16x8 b1 = *(const bf16x8*)(wp + wb + 512);
                    bf16x8 b2 = *(const bf16x8*)(wp + wb + 1024);
                    bf16x8 b3 = *(const bf16x8*)(wp + wb + 1536);
                    int au = (((s * 2 + h) * 3 + dy) * W + dx + wm * 64 + lm) * 8;
                    bf16x8 a0 = *(const bf16x8*)(lA + au);
                    bf16x8 a1 = *(const bf16x8*)(lA + au + 256);
                    acc[0][0] = __builtin_amdgcn_mfma_f32_32x32x16_bf16(a0, b0, acc[0][0], 0, 0, 0);
                    acc[0][1] = __builtin_amdgcn_mfma_f32_32x32x16_bf16(a0, b1, acc[0][1], 0, 0, 0);
                    acc[0][2] = __builtin_amdgcn_mfma_f32_32x32x16_bf16(a0, b2, acc[0][2], 0, 0, 0);
                    acc[0][3] = __builtin_amdgcn_mfma_f32_32x32x16_bf16(a0, b3, acc[0][3], 0, 0, 0);
                    acc[1][0] = __builtin_amdgcn_mfma_f32_32x32x16_bf16(a1, b0, acc[1][0], 0, 0, 0);
                    acc[1][1] = __builtin_amdgcn_mfma_f32_32x32x16_bf16(a1, b1, acc[1][1], 0, 0, 0);
                    acc[1][2] = __builtin_amdgcn_mfma_f32_32x32x16_bf16(a1, b2, acc[1][2], 0, 0, 0);
                    acc[1][3] = __builtin_amdgcn_mfma_f32_32x32x16_bf16(a1, b3, acc[1][3], 0, 0, 0);
                }
    }

    long rowb = (long)(n * 128 + y) * 128;
#pragma unroll
    for (int mf = 0; mf < 2; ++mf)
#pragma unroll
        for (int nf = 0; nf < 4; ++nf) {
            int oc = ocw + nf * 32 + lm;
            float bi = bias[oc];
#pragma unroll
            for (int r = 0; r < 16; ++r) {
                int px = x0 + wm * 64 + mf * 32 + (r & 3) + ((r >> 2) << 3) + (h << 2);
                outp[(rowb + px) * OC + oc] = f2bf(acc[mf][nf][r] + bi);
            }
        }
}

// ---------------------------------------------------------------------------
// BN stats, stage 1: per-block partial (sum, sumsq) per channel over 1024 rows.
// ---------------------------------------------------------------------------
template<int C>
__global__ __launch_bounds__(256) void stats1_k(const u16* __restrict__ h,
                                                float* __restrict__ part) {
    constexpr int CH2 = C / 2;
    constexpr int PARTS = 256 / CH2;
    constexpr int RPB = 1024;
    constexpr int RPT = RPB / PARTS;
    int t = threadIdx.x;
    int chp = t % CH2, rp = t / CH2;
    long row0 = (long)blockIdx.x * RPB + (long)rp * RPT;
    float s0 = 0.f, q0 = 0.f, s1 = 0.f, q1 = 0.f;
    const u16* base = h + row0 * C + chp * 2;
    for (int r = 0; r < RPT; ++r) {
        u32 v = *(const u32*)(base + (long)r * C);
        float a = bf2f((u16)(v & 0xffff));
        float b = bf2f((u16)(v >> 16));
        s0 += a; q0 += a * a; s1 += b; q1 += b * b;
    }
    float4 o = make_float4(s0, q0, s1, q1);
    *(float4*)(part + ((long)(blockIdx.x * PARTS + rp) * CH2 + chp) * 4) = o;
}

template<int C>
__global__ __launch_bounds__(256) void stats2_k(const float* __restrict__ part,
                                                const float* __restrict__ g,
                                                const float* __restrict__ be,
                                                float* __restrict__ ab) {
    constexpr int CH2 = C / 2;
    constexpr int NP = 128 * (256 / CH2);
    int ch = blockIdx.x * 256 + threadIdx.x;
    if (ch >= C) return;
    int chp = ch >> 1, lo = ch & 1;
    float s = 0.f, q = 0.f;
    for (int p = 0; p < NP; ++p) {
        s += part[((long)p * CH2 + chp) * 4 + lo * 2];
        q += part[((long)p * CH2 + chp) * 4 + lo * 2 + 1];
    }
    const float M = 131072.f;
    float mean = s / M;
    float var = q / M - mean * mean;
    float a = g[ch] * rsqrtf(var + 1e-5f);
    ab[ch * 2]     = a;
    ab[ch * 2 + 1] = be[ch] - mean * a;
}

__global__ __launch_bounds__(256) void bn_relu_k(u16* __restrict__ h,
                                                 const float* __restrict__ ab) {
    long idx8 = (long)blockIdx.x * 256 + threadIdx.x;
    u16* p = h + idx8 * 8;
    uint4 v = *(const uint4*)p;
    int chb = ((int)idx8 & 63) << 3;
    u32 w[4] = {v.x, v.y, v.z, v.w};
    u32 o[4];
#pragma unroll
    for (int q = 0; q < 4; ++q) {
        int ch = chb + q * 2;
        float2 a0 = *(const float2*)(ab + ch * 2);
        float2 a1 = *(const float2*)(ab + ch * 2 + 2);
        float f0 = bf2f((u16)(w[q] & 0xffff));
        float f1 = bf2f((u16)(w[q] >> 16));
        f0 = fmaxf(f0 * a0.x + a0.y, 0.f);
        f1 = fmaxf(f1 * a1.x + a1.y, 0.f);
        o[q] = (u32)f2bf(f0) | ((u32)f2bf(f1) << 16);
    }
    *(uint4*)p = make_uint4(o[0], o[1], o[2], o[3]);
}

__global__ __launch_bounds__(256) void inv_conv_k(const u16* __restrict__ h2,
                                                  const float* __restrict__ ab,
                                                  const float* __restrict__ winv,
                                                  const float* __restrict__ binv,
                                                  float* __restrict__ out) {
    __shared__ float lw[8192];   // [256 k][32 oc]
    __shared__ float lab[512];
    int t = threadIdx.x;
    for (int i = t; i < 8192; i += 256) {
        int k = i >> 5, oc = i & 31;
        lw[i] = winv[oc * 256 + k];
    }
    lab[t] = ab[t];
    lab[t + 256] = ab[t + 256];
    __syncthreads();
    long p = (long)blockIdx.x * 256 + t;
    const u16* hp = h2 + p * 256;
    f32x4 acc[8];
    f32x4 zero = {0.f, 0.f, 0.f, 0.f};
#pragma unroll
    for (int q = 0; q < 8; ++q) acc[q] = zero;
    for (int k = 0; k < 256; k += 8) {
        uint4 hv = *(const uint4*)(hp + k);
        u32 wv[4] = {hv.x, hv.y, hv.z, hv.w};
#pragma unroll
        for (int e = 0; e < 8; ++e) {
            u16 us = (e & 1) ? (u16)(wv[e >> 1] >> 16) : (u16)(wv[e >> 1] & 0xffff);
            int kk = k + e;
            float v = bf2f(us);
            v = fmaxf(v * lab[kk * 2] + lab[kk * 2 + 1], 0.f);
            const f32x4* w4 = (const f32x4*)(lw + kk * 32);
#pragma unroll
            for (int q = 0; q < 8; ++q) acc[q] += v * w4[q];
        }
    }
    int n = (int)(p >> 14), rem = (int)(p & 16383);
#pragma unroll
    for (int q = 0; q < 8; ++q)
#pragma unroll
        for (int c = 0; c < 4; ++c) {
            int oc = q * 4 + c;
            out[((long)(n * 32 + oc) << 14) + rem] = acc[q][c] + binv[oc];
        }
}

// ---------------------------------------------------------------------------
// Workspace layout (bytes) — identical footprint to round 0 (~200 MiB):
//   0         w1p   (2,359,296)
//   2359296   w2p   (2,359,296)
//   4718592   part  (524,288)
//   5242880   ab1   (4,096)
//   5246976   ab2   (2,048)
//   5249024   zp    (1,024)  zero page for conv halo
//   8388608   coeffs / h2 (67,108,864)
//   75497472  h1    (134,217,728)
// ---------------------------------------------------------------------------
extern "C" void kernel_launch(void* const* d_in, const int* in_sizes, int n_in,
                              void* d_out, int out_size, void* d_ws, size_t ws_size,
                              hipStream_t stream) {
    const float* x     = (const float*)d_in[0];
    const float* w_dir = (const float*)d_in[1];
    const float* w1    = (const float*)d_in[2];
    const float* b1    = (const float*)d_in[3];
    const float* g1    = (const float*)d_in[4];
    const float* be1   = (const float*)d_in[5];
    const float* w2    = (const float*)d_in[6];
    const float* b2    = (const float*)d_in[7];
    const float* g2    = (const float*)d_in[8];
    const float* be2   = (const float*)d_in[9];
    const float* w_inv = (const float*)d_in[10];
    const float* b_inv = (const float*)d_in[11];
    float* out = (float*)d_out;
    char* ws = (char*)d_ws;

    u16*   w1p  = (u16*)(ws + 0);
    u16*   w2p  = (u16*)(ws + 2359296);
    float* part = (float*)(ws + 4718592);
    float* ab1  = (float*)(ws + 5242880);
    float* ab2  = (float*)(ws + 5246976);
    u16*   zp   = (u16*)(ws + 5249024);
    u16*   coef = (u16*)(ws + 8388608);     // also h2
    u16*   h1   = (u16*)(ws + 75497472);

    hipMemsetAsync(zp, 0, 1024, stream);
    repack_w_k<<<4608, 256, 0, stream>>>(w1, w1p, 512, 256, 1179648);
    repack_w_k<<<4608, 256, 0, stream>>>(w2, w2p, 256, 512, 1179648);
    dir_conv_k<<<4096, 256, 0, stream>>>(x, w_dir, coef);
    conv3_k<256, 512, 1, 4><<<2048, 256, 0, stream>>>(coef, w1p, b1, zp, h1);
    stats1_k<512><<<128, 256, 0, stream>>>(h1, part);
    stats2_k<512><<<2, 256, 0, stream>>>(part, g1, be1, ab1);
    bn_relu_k<<<32768, 256, 0, stream>>>(h1, ab1);
    conv3_k<512, 256, 2, 2><<<1024, 256, 0, stream>>>(h1, w2p, b2, zp, coef);
    stats1_k<256><<<128, 256, 0, stream>>>(coef, part);
    stats2_k<256><<<1, 256, 0, stream>>>(part, g2, be2, ab2);
    inv_conv_k<<<512, 256, 0, stream>>>(coef, ab2, w_inv, b_inv, out);
}

// Round 4
// 911.157 us; speedup vs baseline: 1.5030x; 1.5030x over previous
//
#include <hip/hip_runtime.h>

typedef unsigned short u16;
typedef unsigned int   u32;
typedef __attribute__((ext_vector_type(8)))  __bf16 bf16x8;
typedef __attribute__((ext_vector_type(4)))  float  f32x4;
typedef __attribute__((ext_vector_type(16))) float  f32x16;

__device__ __forceinline__ float bf2f(u16 u) {
    union { u32 i; float f; } v; v.i = ((u32)u) << 16; return v.f;
}
__device__ __forceinline__ u16 f2bf(float f) {
    u32 u = __float_as_uint(f);
    u32 r = (u + 0x7FFFu + ((u >> 16) & 1u)) >> 16;
    return (u16)r;
}

__device__ __forceinline__ void gl16(const u16* g, u16* l) {
    __builtin_amdgcn_global_load_lds(
        (const __attribute__((address_space(1))) unsigned int*)g,
        (__attribute__((address_space(3))) unsigned int*)l, 16, 0, 0);
}

// ---------------------------------------------------------------------------
// Kernel 1: grouped directional conv 5x5, C=32 -> 256, pad=2, no bias.
// x: NCHW f32 (8,32,128,128); out coeffs: NHWC bf16 (8,128,128,256).
// ---------------------------------------------------------------------------
__global__ __launch_bounds__(256) void dir_conv_k(const float* __restrict__ x,
                                                  const float* __restrict__ wd,
                                                  u16* __restrict__ coeffs) {
    int bid = blockIdx.x;
    int cc = bid & 3, y = (bid >> 2) & 127, n = bid >> 9;
    __shared__ float lx[5280];   // [8 c][5 ky][132 xx]
    __shared__ float lw[1600];   // [25 tap][64 oc_local]
    int t = threadIdx.x;
    for (int i = t; i < 1600; i += 256) {
        int ol = i / 25, tap = i - ol * 25;
        lw[tap * 64 + ol] = wd[(cc * 64 + ol) * 25 + tap];
    }
    for (int i = t; i < 5280; i += 256) {
        int c = i / 660, rem = i - c * 660;
        int ky = rem / 132, xx = rem - ky * 132;
        int gy = y - 2 + ky, gx = xx - 2;
        float v = 0.f;
        if (gy >= 0 && gy < 128 && gx >= 0 && gx < 128)
            v = x[(((n * 32 + cc * 8 + c) * 128 + gy) << 7) + gx];
        lx[i] = v;
    }
    __syncthreads();
    int px = t >> 1, oh = t & 1;
    float acc[4][8];
#pragma unroll
    for (int j = 0; j < 4; ++j)
#pragma unroll
        for (int d = 0; d < 8; ++d) acc[j][d] = 0.f;
#pragma unroll
    for (int j = 0; j < 4; ++j) {
        int cl = oh * 4 + j;
        const float* lxc = &lx[cl * 660];
#pragma unroll
        for (int ky = 0; ky < 5; ++ky)
#pragma unroll
            for (int kx = 0; kx < 5; ++kx) {
                float xv = lxc[ky * 132 + px + kx];
                const float* w8 = &lw[(ky * 5 + kx) * 64 + cl * 8];
#pragma unroll
                for (int d = 0; d < 8; ++d) acc[j][d] += xv * w8[d];
            }
    }
    long base = ((long)((n * 128 + y) * 128 + px)) * 256 + cc * 64 + oh * 32;
#pragma unroll
    for (int j = 0; j < 4; ++j) {
        uint4 o;
        o.x = (u32)f2bf(acc[j][0]) | ((u32)f2bf(acc[j][1]) << 16);
        o.y = (u32)f2bf(acc[j][2]) | ((u32)f2bf(acc[j][3]) << 16);
        o.z = (u32)f2bf(acc[j][4]) | ((u32)f2bf(acc[j][5]) << 16);
        o.w = (u32)f2bf(acc[j][6]) | ((u32)f2bf(acc[j][7]) << 16);
        *(uint4*)(coeffs + base + j * 8) = o;
    }
}

// ---------------------------------------------------------------------------
// Repack conv weights OIHW f32 -> 32x32x16 B-fragment-order bf16:
// wp[((((tap*KC+kc)*2+s)*OC+oc)*2+h)*8 + j] = w[oc][kc*32+s*16+h*8+j][tap]
// ---------------------------------------------------------------------------
__global__ __launch_bounds__(256) void repack_w_k(const float* __restrict__ w,
                                                  u16* __restrict__ wp,
                                                  int OC, int IC, int total) {
    int f = blockIdx.x * 256 + threadIdx.x;
    if (f >= total) return;
    int KC = IC >> 5;
    int j  = f & 7;
    int h  = (f >> 3) & 1;
    int g  = f >> 4;           // ((tap*KC+kc)*2+s)*OC + oc
    int oc = g % OC; g /= OC;
    int s  = g & 1;  g >>= 1;  // tap*KC + kc
    int kc = g % KC;
    int tap = g / KC;
    int ic = kc * 32 + s * 16 + h * 8 + j;
    wp[f] = f2bf(w[(oc * IC + ic) * 9 + tap]);
}

// ---------------------------------------------------------------------------
// 3x3 conv, NHWC bf16 in/out, implicit GEMM with mfma_f32_32x32x16_bf16.
// Block tile: 128 px (one full image row) x 256 oc; 4 waves (2m x 2n),
// each wave 64px x 128oc (2x4 frags of 32x32, acc = 128 regs).
// 2-phase pipeline: double-buffered A in LDS via global_load_lds; stage
// kc+1 right after the barrier so the syncthreads vmcnt-drain is free.
// B read from global in exact fragment order (L2-resident).
// ---------------------------------------------------------------------------
template<int IC, int OC>
__global__ __launch_bounds__(256, 2) void conv3_k(const u16* __restrict__ in,
                                                  const u16* __restrict__ wp,
                                                  const float* __restrict__ bias,
                                                  const u16* __restrict__ zp,
                                                  u16* __restrict__ outp) {
    constexpr int KC = IC / 32;
    constexpr int W  = 130;             // 128 px + halo
    constexpr int TU = 12 * W;          // 1560 16B staging units per buffer
    constexpr int NFULL = TU / 256;     // 6
    constexpr int REM   = TU % 256;     // 24
    __shared__ u16 lA0[TU * 8];
    __shared__ u16 lA1[TU * 8];

    int bx = blockIdx.x;
    int y = bx & 127, n = bx >> 7;
    int ocb = blockIdx.y;
    int t = threadIdx.x, lane = t & 63, wv = t >> 6;
    int wm = wv & 1, wn = wv >> 1;
    int lm = lane & 31, h = lane >> 5;
    int ocw = ocb * 256 + wn * 128;

    // per-lane staging source pointers (kc-invariant part)
    const u16* ptrs[NFULL + 1];
#pragma unroll
    for (int i = 0; i <= NFULL; ++i) {
        int u = (i == NFULL) ? (NFULL * 256 + lane) : (i * 256 + wv * 64 + lane);
        int icq = u / (3 * W);
        int r2  = u - icq * (3 * W);
        int dy  = r2 / W;
        int xx  = r2 - dy * W;
        int gy = y - 1 + dy, gx = xx - 1;
        bool ok = ((unsigned)gy < 128u) && ((unsigned)gx < 128u);
        ptrs[i] = ok ? (in + (long)((n * 128 + gy) * 128 + gx) * IC + (icq & 3) * 8)
                     : zp;
    }

    auto stage = [&](u16* dst, int kc) {
#pragma unroll
        for (int i = 0; i < NFULL; ++i)
            gl16(ptrs[i] + kc * 32, dst + (i * 256 + wv * 64) * 8);
        if (wv == 0 && lane < REM)
            gl16(ptrs[NFULL] + kc * 32, dst + NFULL * 256 * 8);
    };

    f32x16 acc[2][4];
#pragma unroll
    for (int mf = 0; mf < 2; ++mf)
#pragma unroll
        for (int nf = 0; nf < 4; ++nf)
#pragma unroll
            for (int r = 0; r < 16; ++r) acc[mf][nf][r] = 0.f;

    auto compute = [&](const u16* lAu, int kc) {
#pragma unroll
        for (int dy = 0; dy < 3; ++dy)
#pragma unroll
            for (int dx = 0; dx < 3; ++dx)
#pragma unroll
                for (int s = 0; s < 2; ++s) {
                    int tap = dy * 3 + dx;
                    long wb = (((long)(tap * KC + kc) * 2 + s) * OC
                               + ocw + lm) * 16 + h * 8;
                    bf16x8 b0 = *(const bf16x8*)(wp + wb);
                    bf16x8 b1 = *(const bf16x8*)(wp + wb + 512);
                    bf16x8 b2 = *(const bf16x8*)(wp + wb + 1024);
                    bf16x8 b3 = *(const bf16x8*)(wp + wb + 1536);
                    int au = (((s * 2 + h) * 3 + dy) * W + dx + wm * 64 + lm) * 8;
                    bf16x8 a0 = *(const bf16x8*)(lAu + au);
                    bf16x8 a1 = *(const bf16x8*)(lAu + au + 256);
                    acc[0][0] = __builtin_amdgcn_mfma_f32_32x32x16_bf16(a0, b0, acc[0][0], 0, 0, 0);
                    acc[0][1] = __builtin_amdgcn_mfma_f32_32x32x16_bf16(a0, b1, acc[0][1], 0, 0, 0);
                    acc[0][2] = __builtin_amdgcn_mfma_f32_32x32x16_bf16(a0, b2, acc[0][2], 0, 0, 0);
                    acc[0][3] = __builtin_amdgcn_mfma_f32_32x32x16_bf16(a0, b3, acc[0][3], 0, 0, 0);
                    acc[1][0] = __builtin_amdgcn_mfma_f32_32x32x16_bf16(a1, b0, acc[1][0], 0, 0, 0);
                    acc[1][1] = __builtin_amdgcn_mfma_f32_32x32x16_bf16(a1, b1, acc[1][1], 0, 0, 0);
                    acc[1][2] = __builtin_amdgcn_mfma_f32_32x32x16_bf16(a1, b2, acc[1][2], 0, 0, 0);
                    acc[1][3] = __builtin_amdgcn_mfma_f32_32x32x16_bf16(a1, b3, acc[1][3], 0, 0, 0);
                }
    };

    stage(lA0, 0);
    for (int kc = 0; kc < KC; kc += 2) {
        __syncthreads();                 // drains lA0 staging (in flight during prev compute)
        stage(lA1, kc + 1);              // fly during compute(lA0)
        compute(lA0, kc);
        __syncthreads();                 // drains lA1 staging
        if (kc + 2 < KC) stage(lA0, kc + 2);
        compute(lA1, kc + 1);
    }

    long rowb = (long)(n * 128 + y) * 128;
#pragma unroll
    for (int mf = 0; mf < 2; ++mf)
#pragma unroll
        for (int nf = 0; nf < 4; ++nf) {
            int oc = ocw + nf * 32 + lm;
            float bi = bias[oc];
#pragma unroll
            for (int r = 0; r < 16; ++r) {
                int px = wm * 64 + mf * 32 + (r & 3) + ((r >> 2) << 3) + (h << 2);
                outp[(rowb + px) * OC + oc] = f2bf(acc[mf][nf][r] + bi);
            }
        }
}

// ---------------------------------------------------------------------------
// BN stats, stage 1: per-block partial (sum, sumsq) per channel over 1024 rows.
// ---------------------------------------------------------------------------
template<int C>
__global__ __launch_bounds__(256) void stats1_k(const u16* __restrict__ h,
                                                float* __restrict__ part) {
    constexpr int CH2 = C / 2;
    constexpr int PARTS = 256 / CH2;
    constexpr int RPB = 1024;
    constexpr int RPT = RPB / PARTS;
    int t = threadIdx.x;
    int chp = t % CH2, rp = t / CH2;
    long row0 = (long)blockIdx.x * RPB + (long)rp * RPT;
    float s0 = 0.f, q0 = 0.f, s1 = 0.f, q1 = 0.f;
    const u16* base = h + row0 * C + chp * 2;
    for (int r = 0; r < RPT; ++r) {
        u32 v = *(const u32*)(base + (long)r * C);
        float a = bf2f((u16)(v & 0xffff));
        float b = bf2f((u16)(v >> 16));
        s0 += a; q0 += a * a; s1 += b; q1 += b * b;
    }
    float4 o = make_float4(s0, q0, s1, q1);
    *(float4*)(part + ((long)(blockIdx.x * PARTS + rp) * CH2 + chp) * 4) = o;
}

template<int C>
__global__ __launch_bounds__(256) void stats2_k(const float* __restrict__ part,
                                                const float* __restrict__ g,
                                                const float* __restrict__ be,
                                                float* __restrict__ ab) {
    constexpr int CH2 = C / 2;
    constexpr int NP = 128 * (256 / CH2);
    int ch = blockIdx.x * 256 + threadIdx.x;
    if (ch >= C) return;
    int chp = ch >> 1, lo = ch & 1;
    float s = 0.f, q = 0.f;
    for (int p = 0; p < NP; ++p) {
        s += part[((long)p * CH2 + chp) * 4 + lo * 2];
        q += part[((long)p * CH2 + chp) * 4 + lo * 2 + 1];
    }
    const float M = 131072.f;
    float mean = s / M;
    float var = q / M - mean * mean;
    float a = g[ch] * rsqrtf(var + 1e-5f);
    ab[ch * 2]     = a;
    ab[ch * 2 + 1] = be[ch] - mean * a;
}

__global__ __launch_bounds__(256) void bn_relu_k(u16* __restrict__ h,
                                                 const float* __restrict__ ab) {
    long idx8 = (long)blockIdx.x * 256 + threadIdx.x;
    u16* p = h + idx8 * 8;
    uint4 v = *(const uint4*)p;
    int chb = ((int)idx8 & 63) << 3;
    u32 w[4] = {v.x, v.y, v.z, v.w};
    u32 o[4];
#pragma unroll
    for (int q = 0; q < 4; ++q) {
        int ch = chb + q * 2;
        float2 a0 = *(const float2*)(ab + ch * 2);
        float2 a1 = *(const float2*)(ab + ch * 2 + 2);
        float f0 = bf2f((u16)(w[q] & 0xffff));
        float f1 = bf2f((u16)(w[q] >> 16));
        f0 = fmaxf(f0 * a0.x + a0.y, 0.f);
        f1 = fmaxf(f1 * a1.x + a1.y, 0.f);
        o[q] = (u32)f2bf(f0) | ((u32)f2bf(f1) << 16);
    }
    *(uint4*)p = make_uint4(o[0], o[1], o[2], o[3]);
}

__global__ __launch_bounds__(256) void inv_conv_k(const u16* __restrict__ h2,
                                                  const float* __restrict__ ab,
                                                  const float* __restrict__ winv,
                                                  const float* __restrict__ binv,
                                                  float* __restrict__ out) {
    __shared__ float lw[8192];   // [256 k][32 oc]
    __shared__ float lab[512];
    int t = threadIdx.x;
    for (int i = t; i < 8192; i += 256) {
        int k = i >> 5, oc = i & 31;
        lw[i] = winv[oc * 256 + k];
    }
    lab[t] = ab[t];
    lab[t + 256] = ab[t + 256];
    __syncthreads();
    long p = (long)blockIdx.x * 256 + t;
    const u16* hp = h2 + p * 256;
    f32x4 acc[8];
    f32x4 zero = {0.f, 0.f, 0.f, 0.f};
#pragma unroll
    for (int q = 0; q < 8; ++q) acc[q] = zero;
    for (int k = 0; k < 256; k += 8) {
        uint4 hv = *(const uint4*)(hp + k);
        u32 wv[4] = {hv.x, hv.y, hv.z, hv.w};
#pragma unroll
        for (int e = 0; e < 8; ++e) {
            u16 us = (e & 1) ? (u16)(wv[e >> 1] >> 16) : (u16)(wv[e >> 1] & 0xffff);
            int kk = k + e;
            float v = bf2f(us);
            v = fmaxf(v * lab[kk * 2] + lab[kk * 2 + 1], 0.f);
            const f32x4* w4 = (const f32x4*)(lw + kk * 32);
#pragma unroll
            for (int q = 0; q < 8; ++q) acc[q] += v * w4[q];
        }
    }
    int n = (int)(p >> 14), rem = (int)(p & 16383);
#pragma unroll
    for (int q = 0; q < 8; ++q)
#pragma unroll
        for (int c = 0; c < 4; ++c) {
            int oc = q * 4 + c;
            out[((long)(n * 32 + oc) << 14) + rem] = acc[q][c] + binv[oc];
        }
}

// ---------------------------------------------------------------------------
// Workspace layout (bytes) — ~200 MiB:
//   0         w1p   (2,359,296)
//   2359296   w2p   (2,359,296)
//   4718592   part  (524,288)
//   5242880   ab1   (4,096)
//   5246976   ab2   (2,048)
//   5249024   zp    (1,024)  zero page for conv halo
//   8388608   coeffs / h2 (67,108,864)
//   75497472  h1    (134,217,728)
// ---------------------------------------------------------------------------
extern "C" void kernel_launch(void* const* d_in, const int* in_sizes, int n_in,
                              void* d_out, int out_size, void* d_ws, size_t ws_size,
                              hipStream_t stream) {
    const float* x     = (const float*)d_in[0];
    const float* w_dir = (const float*)d_in[1];
    const float* w1    = (const float*)d_in[2];
    const float* b1    = (const float*)d_in[3];
    const float* g1    = (const float*)d_in[4];
    const float* be1   = (const float*)d_in[5];
    const float* w2    = (const float*)d_in[6];
    const float* b2    = (const float*)d_in[7];
    const float* g2    = (const float*)d_in[8];
    const float* be2   = (const float*)d_in[9];
    const float* w_inv = (const float*)d_in[10];
    const float* b_inv = (const float*)d_in[11];
    float* out = (float*)d_out;
    char* ws = (char*)d_ws;

    u16*   w1p  = (u16*)(ws + 0);
    u16*   w2p  = (u16*)(ws + 2359296);
    float* part = (float*)(ws + 4718592);
    float* ab1  = (float*)(ws + 5242880);
    float* ab2  = (float*)(ws + 5246976);
    u16*   zp   = (u16*)(ws + 5249024);
    u16*   coef = (u16*)(ws + 8388608);     // also h2
    u16*   h1   = (u16*)(ws + 75497472);

    hipMemsetAsync(zp, 0, 1024, stream);
    repack_w_k<<<4608, 256, 0, stream>>>(w1, w1p, 512, 256, 1179648);
    repack_w_k<<<4608, 256, 0, stream>>>(w2, w2p, 256, 512, 1179648);
    dir_conv_k<<<4096, 256, 0, stream>>>(x, w_dir, coef);
    conv3_k<256, 512><<<dim3(1024, 2), 256, 0, stream>>>(coef, w1p, b1, zp, h1);
    stats1_k<512><<<128, 256, 0, stream>>>(h1, part);
    stats2_k<512><<<2, 256, 0, stream>>>(part, g1, be1, ab1);
    bn_relu_k<<<32768, 256, 0, stream>>>(h1, ab1);
    conv3_k<512, 256><<<dim3(1024, 1), 256, 0, stream>>>(h1, w2p, b2, zp, coef);
    stats1_k<256><<<128, 256, 0, stream>>>(coef, part);
    stats2_k<256><<<1, 256, 0, stream>>>(part, g2, be2, ab2);
    inv_conv_k<<<512, 256, 0, stream>>>(coef, ab2, w_inv, b_inv, out);
}

// Round 5
// 902.439 us; speedup vs baseline: 1.5175x; 1.0097x over previous
//
#include <hip/hip_runtime.h>

typedef unsigned short u16;
typedef unsigned int   u32;
typedef __attribute__((ext_vector_type(8)))  __bf16 bf16x8;
typedef __attribute__((ext_vector_type(4)))  float  f32x4;
typedef __attribute__((ext_vector_type(16))) float  f32x16;

__device__ __forceinline__ float bf2f(u16 u) {
    union { u32 i; float f; } v; v.i = ((u32)u) << 16; return v.f;
}
__device__ __forceinline__ u16 f2bf(float f) {
    u32 u = __float_as_uint(f);
    u32 r = (u + 0x7FFFu + ((u >> 16) & 1u)) >> 16;
    return (u16)r;
}

__device__ __forceinline__ void gl16(const u16* g, u16* l) {
    __builtin_amdgcn_global_load_lds(
        (const __attribute__((address_space(1))) unsigned int*)g,
        (__attribute__((address_space(3))) unsigned int*)l, 16, 0, 0);
}

// ---------------------------------------------------------------------------
// Kernel 1: grouped directional conv 5x5, C=32 -> 256, pad=2, no bias.
// x: NCHW f32 (8,32,128,128); out coeffs: NHWC bf16 (8,128,128,256).
// ---------------------------------------------------------------------------
__global__ __launch_bounds__(256) void dir_conv_k(const float* __restrict__ x,
                                                  const float* __restrict__ wd,
                                                  u16* __restrict__ coeffs) {
    int bid = blockIdx.x;
    int cc = bid & 3, y = (bid >> 2) & 127, n = bid >> 9;
    __shared__ float lx[5280];   // [8 c][5 ky][132 xx]
    __shared__ float lw[1600];   // [25 tap][64 oc_local]
    int t = threadIdx.x;
    for (int i = t; i < 1600; i += 256) {
        int ol = i / 25, tap = i - ol * 25;
        lw[tap * 64 + ol] = wd[(cc * 64 + ol) * 25 + tap];
    }
    for (int i = t; i < 5280; i += 256) {
        int c = i / 660, rem = i - c * 660;
        int ky = rem / 132, xx = rem - ky * 132;
        int gy = y - 2 + ky, gx = xx - 2;
        float v = 0.f;
        if (gy >= 0 && gy < 128 && gx >= 0 && gx < 128)
            v = x[(((n * 32 + cc * 8 + c) * 128 + gy) << 7) + gx];
        lx[i] = v;
    }
    __syncthreads();
    int px = t >> 1, oh = t & 1;
    float acc[4][8];
#pragma unroll
    for (int j = 0; j < 4; ++j)
#pragma unroll
        for (int d = 0; d < 8; ++d) acc[j][d] = 0.f;
#pragma unroll
    for (int j = 0; j < 4; ++j) {
        int cl = oh * 4 + j;
        const float* lxc = &lx[cl * 660];
#pragma unroll
        for (int ky = 0; ky < 5; ++ky)
#pragma unroll
            for (int kx = 0; kx < 5; ++kx) {
                float xv = lxc[ky * 132 + px + kx];
                const float* w8 = &lw[(ky * 5 + kx) * 64 + cl * 8];
#pragma unroll
                for (int d = 0; d < 8; ++d) acc[j][d] += xv * w8[d];
            }
    }
    long base = ((long)((n * 128 + y) * 128 + px)) * 256 + cc * 64 + oh * 32;
#pragma unroll
    for (int j = 0; j < 4; ++j) {
        uint4 o;
        o.x = (u32)f2bf(acc[j][0]) | ((u32)f2bf(acc[j][1]) << 16);
        o.y = (u32)f2bf(acc[j][2]) | ((u32)f2bf(acc[j][3]) << 16);
        o.z = (u32)f2bf(acc[j][4]) | ((u32)f2bf(acc[j][5]) << 16);
        o.w = (u32)f2bf(acc[j][6]) | ((u32)f2bf(acc[j][7]) << 16);
        *(uint4*)(coeffs + base + j * 8) = o;
    }
}

// ---------------------------------------------------------------------------
// Repack conv weights OIHW f32 -> 32x32x16 B-fragment-order bf16:
// wp[((((tap*KC+kc)*2+s)*OC+oc)*2+h)*8 + j] = w[oc][kc*32+s*16+h*8+j][tap]
// ---------------------------------------------------------------------------
__global__ __launch_bounds__(256) void repack_w_k(const float* __restrict__ w,
                                                  u16* __restrict__ wp,
                                                  int OC, int IC, int total) {
    int f = blockIdx.x * 256 + threadIdx.x;
    if (f >= total) return;
    int KC = IC >> 5;
    int j  = f & 7;
    int h  = (f >> 3) & 1;
    int g  = f >> 4;           // ((tap*KC+kc)*2+s)*OC + oc
    int oc = g % OC; g /= OC;
    int s  = g & 1;  g >>= 1;  // tap*KC + kc
    int kc = g % KC;
    int tap = g / KC;
    int ic = kc * 32 + s * 16 + h * 8 + j;
    wp[f] = f2bf(w[(oc * IC + ic) * 9 + tap]);
}

// ---------------------------------------------------------------------------
// 3x3 conv, NHWC bf16 in/out, implicit GEMM with mfma_f32_32x32x16_bf16.
// Block tile: 128 px (one image row) x 256 oc; 8 waves (512 thr, 2wm x 4wn),
// wave tile 64px x 64oc (2x2 frags of 32x32, acc = 64 regs) -> 4 waves/SIMD.
// 2-phase pipeline: double-buffered A in LDS via global_load_lds; stage kc+1
// right after the barrier so the syncthreads vmcnt-drain overlaps compute.
// B read from global in exact fragment order (L2-resident).
// ---------------------------------------------------------------------------
template<int IC, int OC>
__global__ __launch_bounds__(512, 4) void conv3_k(const u16* __restrict__ in,
                                                  const u16* __restrict__ wp,
                                                  const float* __restrict__ bias,
                                                  const u16* __restrict__ zp,
                                                  u16* __restrict__ outp) {
    constexpr int KC = IC / 32;
    constexpr int W  = 130;             // 128 px + halo
    constexpr int TU = 12 * W;          // 1560 16B staging units per buffer
    constexpr int NFULL = TU / 512;     // 3
    constexpr int REM   = TU % 512;     // 24
    __shared__ u16 lA0[TU * 8];
    __shared__ u16 lA1[TU * 8];

    int bx = blockIdx.x;
    int y = bx & 127, n = bx >> 7;
    int ocb = blockIdx.y;
    int t = threadIdx.x, lane = t & 63, wv = t >> 6;
    int wm = wv & 1, wn = wv >> 1;
    int lm = lane & 31, h = lane >> 5;
    int ocw = ocb * 256 + wn * 64;

    // per-lane staging source pointers (kc-invariant part)
    const u16* ptrs[NFULL + 1];
#pragma unroll
    for (int i = 0; i <= NFULL; ++i) {
        int u = (i == NFULL) ? (NFULL * 512 + lane) : (i * 512 + t);
        int icq = u / (3 * W);
        int r2  = u - icq * (3 * W);
        int dy  = r2 / W;
        int xx  = r2 - dy * W;
        int gy = y - 1 + dy, gx = xx - 1;
        bool ok = ((unsigned)gy < 128u) && ((unsigned)gx < 128u);
        ptrs[i] = ok ? (in + (long)((n * 128 + gy) * 128 + gx) * IC + (icq & 3) * 8)
                     : zp;
    }

    auto stage = [&](u16* dst, int kc) {
#pragma unroll
        for (int i = 0; i < NFULL; ++i)
            gl16(ptrs[i] + kc * 32, dst + (i * 512 + wv * 64) * 8);
        if (wv == 0 && lane < REM)
            gl16(ptrs[NFULL] + kc * 32, dst + NFULL * 512 * 8);
    };

    f32x16 acc[2][2];
#pragma unroll
    for (int mf = 0; mf < 2; ++mf)
#pragma unroll
        for (int nf = 0; nf < 2; ++nf)
#pragma unroll
            for (int r = 0; r < 16; ++r) acc[mf][nf][r] = 0.f;

    auto compute = [&](const u16* lAu, int kc) {
#pragma unroll
        for (int dy = 0; dy < 3; ++dy)
#pragma unroll
            for (int dx = 0; dx < 3; ++dx)
#pragma unroll
                for (int s = 0; s < 2; ++s) {
                    int tap = dy * 3 + dx;
                    long wb = (((long)(tap * KC + kc) * 2 + s) * OC
                               + ocw + lm) * 16 + h * 8;
                    bf16x8 b0 = *(const bf16x8*)(wp + wb);
                    bf16x8 b1 = *(const bf16x8*)(wp + wb + 512);  // oc + 32
                    int au = (((s * 2 + h) * 3 + dy) * W + dx + wm * 64 + lm) * 8;
                    bf16x8 a0 = *(const bf16x8*)(lAu + au);
                    bf16x8 a1 = *(const bf16x8*)(lAu + au + 256); // px + 32
                    acc[0][0] = __builtin_amdgcn_mfma_f32_32x32x16_bf16(a0, b0, acc[0][0], 0, 0, 0);
                    acc[0][1] = __builtin_amdgcn_mfma_f32_32x32x16_bf16(a0, b1, acc[0][1], 0, 0, 0);
                    acc[1][0] = __builtin_amdgcn_mfma_f32_32x32x16_bf16(a1, b0, acc[1][0], 0, 0, 0);
                    acc[1][1] = __builtin_amdgcn_mfma_f32_32x32x16_bf16(a1, b1, acc[1][1], 0, 0, 0);
                }
    };

    stage(lA0, 0);
    for (int kc = 0; kc < KC; kc += 2) {
        __syncthreads();                 // drains lA0 staging
        stage(lA1, kc + 1);              // fly during compute(lA0)
        compute(lA0, kc);
        __syncthreads();                 // drains lA1 staging
        if (kc + 2 < KC) stage(lA0, kc + 2);
        compute(lA1, kc + 1);
    }

    long rowb = (long)(n * 128 + y) * 128;
#pragma unroll
    for (int mf = 0; mf < 2; ++mf)
#pragma unroll
        for (int nf = 0; nf < 2; ++nf) {
            int oc = ocw + nf * 32 + lm;
            float bi = bias[oc];
#pragma unroll
            for (int r = 0; r < 16; ++r) {
                int px = wm * 64 + mf * 32 + (r & 3) + ((r >> 2) << 3) + (h << 2);
                outp[(rowb + px) * OC + oc] = f2bf(acc[mf][nf][r] + bi);
            }
        }
}

// ---------------------------------------------------------------------------
// BN stats, stage 1: per-block partial (sum, sumsq) per channel over 1024 rows.
// ---------------------------------------------------------------------------
template<int C>
__global__ __launch_bounds__(256) void stats1_k(const u16* __restrict__ h,
                                                float* __restrict__ part) {
    constexpr int CH2 = C / 2;
    constexpr int PARTS = 256 / CH2;
    constexpr int RPB = 1024;
    constexpr int RPT = RPB / PARTS;
    int t = threadIdx.x;
    int chp = t % CH2, rp = t / CH2;
    long row0 = (long)blockIdx.x * RPB + (long)rp * RPT;
    float s0 = 0.f, q0 = 0.f, s1 = 0.f, q1 = 0.f;
    const u16* base = h + row0 * C + chp * 2;
    for (int r = 0; r < RPT; ++r) {
        u32 v = *(const u32*)(base + (long)r * C);
        float a = bf2f((u16)(v & 0xffff));
        float b = bf2f((u16)(v >> 16));
        s0 += a; q0 += a * a; s1 += b; q1 += b * b;
    }
    float4 o = make_float4(s0, q0, s1, q1);
    *(float4*)(part + ((long)(blockIdx.x * PARTS + rp) * CH2 + chp) * 4) = o;
}

template<int C>
__global__ __launch_bounds__(256) void stats2_k(const float* __restrict__ part,
                                                const float* __restrict__ g,
                                                const float* __restrict__ be,
                                                float* __restrict__ ab) {
    constexpr int CH2 = C / 2;
    constexpr int NP = 128 * (256 / CH2);
    int ch = blockIdx.x * 256 + threadIdx.x;
    if (ch >= C) return;
    int chp = ch >> 1, lo = ch & 1;
    float s = 0.f, q = 0.f;
    for (int p = 0; p < NP; ++p) {
        s += part[((long)p * CH2 + chp) * 4 + lo * 2];
        q += part[((long)p * CH2 + chp) * 4 + lo * 2 + 1];
    }
    const float M = 131072.f;
    float mean = s / M;
    float var = q / M - mean * mean;
    float a = g[ch] * rsqrtf(var + 1e-5f);
    ab[ch * 2]     = a;
    ab[ch * 2 + 1] = be[ch] - mean * a;
}

__global__ __launch_bounds__(256) void bn_relu_k(u16* __restrict__ h,
                                                 const float* __restrict__ ab) {
    long idx8 = (long)blockIdx.x * 256 + threadIdx.x;
    u16* p = h + idx8 * 8;
    uint4 v = *(const uint4*)p;
    int chb = ((int)idx8 & 63) << 3;
    u32 w[4] = {v.x, v.y, v.z, v.w};
    u32 o[4];
#pragma unroll
    for (int q = 0; q < 4; ++q) {
        int ch = chb + q * 2;
        float2 a0 = *(const float2*)(ab + ch * 2);
        float2 a1 = *(const float2*)(ab + ch * 2 + 2);
        float f0 = bf2f((u16)(w[q] & 0xffff));
        float f1 = bf2f((u16)(w[q] >> 16));
        f0 = fmaxf(f0 * a0.x + a0.y, 0.f);
        f1 = fmaxf(f1 * a1.x + a1.y, 0.f);
        o[q] = (u32)f2bf(f0) | ((u32)f2bf(f1) << 16);
    }
    *(uint4*)p = make_uint4(o[0], o[1], o[2], o[3]);
}

__global__ __launch_bounds__(256) void inv_conv_k(const u16* __restrict__ h2,
                                                  const float* __restrict__ ab,
                                                  const float* __restrict__ winv,
                                                  const float* __restrict__ binv,
                                                  float* __restrict__ out) {
    __shared__ float lw[8192];   // [256 k][32 oc]
    __shared__ float lab[512];
    int t = threadIdx.x;
    for (int i = t; i < 8192; i += 256) {
        int k = i >> 5, oc = i & 31;
        lw[i] = winv[oc * 256 + k];
    }
    lab[t] = ab[t];
    lab[t + 256] = ab[t + 256];
    __syncthreads();
    long p = (long)blockIdx.x * 256 + t;
    const u16* hp = h2 + p * 256;
    f32x4 acc[8];
    f32x4 zero = {0.f, 0.f, 0.f, 0.f};
#pragma unroll
    for (int q = 0; q < 8; ++q) acc[q] = zero;
    for (int k = 0; k < 256; k += 8) {
        uint4 hv = *(const uint4*)(hp + k);
        u32 wv[4] = {hv.x, hv.y, hv.z, hv.w};
#pragma unroll
        for (int e = 0; e < 8; ++e) {
            u16 us = (e & 1) ? (u16)(wv[e >> 1] >> 16) : (u16)(wv[e >> 1] & 0xffff);
            int kk = k + e;
            float v = bf2f(us);
            v = fmaxf(v * lab[kk * 2] + lab[kk * 2 + 1], 0.f);
            const f32x4* w4 = (const f32x4*)(lw + kk * 32);
#pragma unroll
            for (int q = 0; q < 8; ++q) acc[q] += v * w4[q];
        }
    }
    int n = (int)(p >> 14), rem = (int)(p & 16383);
#pragma unroll
    for (int q = 0; q < 8; ++q)
#pragma unroll
        for (int c = 0; c < 4; ++c) {
            int oc = q * 4 + c;
            out[((long)(n * 32 + oc) << 14) + rem] = acc[q][c] + binv[oc];
        }
}

// ---------------------------------------------------------------------------
// Workspace layout (bytes) — ~200 MiB:
//   0         w1p   (2,359,296)
//   2359296   w2p   (2,359,296)
//   4718592   part  (524,288)
//   5242880   ab1   (4,096)
//   5246976   ab2   (2,048)
//   5249024   zp    (1,024)  zero page for conv halo
//   8388608   coeffs / h2 (67,108,864)
//   75497472  h1    (134,217,728)
// ---------------------------------------------------------------------------
extern "C" void kernel_launch(void* const* d_in, const int* in_sizes, int n_in,
                              void* d_out, int out_size, void* d_ws, size_t ws_size,
                              hipStream_t stream) {
    const float* x     = (const float*)d_in[0];
    const float* w_dir = (const float*)d_in[1];
    const float* w1    = (const float*)d_in[2];
    const float* b1    = (const float*)d_in[3];
    const float* g1    = (const float*)d_in[4];
    const float* be1   = (const float*)d_in[5];
    const float* w2    = (const float*)d_in[6];
    const float* b2    = (const float*)d_in[7];
    const float* g2    = (const float*)d_in[8];
    const float* be2   = (const float*)d_in[9];
    const float* w_inv = (const float*)d_in[10];
    const float* b_inv = (const float*)d_in[11];
    float* out = (float*)d_out;
    char* ws = (char*)d_ws;

    u16*   w1p  = (u16*)(ws + 0);
    u16*   w2p  = (u16*)(ws + 2359296);
    float* part = (float*)(ws + 4718592);
    float* ab1  = (float*)(ws + 5242880);
    float* ab2  = (float*)(ws + 5246976);
    u16*   zp   = (u16*)(ws + 5249024);
    u16*   coef = (u16*)(ws + 8388608);     // also h2
    u16*   h1   = (u16*)(ws + 75497472);

    hipMemsetAsync(zp, 0, 1024, stream);
    repack_w_k<<<4608, 256, 0, stream>>>(w1, w1p, 512, 256, 1179648);
    repack_w_k<<<4608, 256, 0, stream>>>(w2, w2p, 256, 512, 1179648);
    dir_conv_k<<<4096, 256, 0, stream>>>(x, w_dir, coef);
    conv3_k<256, 512><<<dim3(1024, 2), 512, 0, stream>>>(coef, w1p, b1, zp, h1);
    stats1_k<512><<<128, 256, 0, stream>>>(h1, part);
    stats2_k<512><<<2, 256, 0, stream>>>(part, g1, be1, ab1);
    bn_relu_k<<<32768, 256, 0, stream>>>(h1, ab1);
    conv3_k<512, 256><<<dim3(1024, 1), 512, 0, stream>>>(h1, w2p, b2, zp, coef);
    stats1_k<256><<<128, 256, 0, stream>>>(coef, part);
    stats2_k<256><<<1, 256, 0, stream>>>(part, g2, be2, ab2);
    inv_conv_k<<<512, 256, 0, stream>>>(coef, ab2, w_inv, b_inv, out);
}

// Round 6
// 821.143 us; speedup vs baseline: 1.6678x; 1.0990x over previous
//
#include <hip/hip_runtime.h>

typedef unsigned short u16;
typedef unsigned int   u32;
typedef __attribute__((ext_vector_type(8)))  __bf16 bf16x8;
typedef __attribute__((ext_vector_type(4)))  float  f32x4;
typedef __attribute__((ext_vector_type(16))) float  f32x16;

__device__ __forceinline__ float bf2f(u16 u) {
    union { u32 i; float f; } v; v.i = ((u32)u) << 16; return v.f;
}
__device__ __forceinline__ u16 f2bf(float f) {
    u32 u = __float_as_uint(f);
    u32 r = (u + 0x7FFFu + ((u >> 16) & 1u)) >> 16;
    return (u16)r;
}

__device__ __forceinline__ void gl16(const u16* g, u16* l) {
    __builtin_amdgcn_global_load_lds(
        (const __attribute__((address_space(1))) unsigned int*)g,
        (__attribute__((address_space(3))) unsigned int*)l, 16, 0, 0);
}

// ---------------------------------------------------------------------------
// Kernel 1: grouped directional conv 5x5, C=32 -> 256, pad=2, no bias.
// ---------------------------------------------------------------------------
__global__ __launch_bounds__(256) void dir_conv_k(const float* __restrict__ x,
                                                  const float* __restrict__ wd,
                                                  u16* __restrict__ coeffs) {
    int bid = blockIdx.x;
    int cc = bid & 3, y = (bid >> 2) & 127, n = bid >> 9;
    __shared__ float lx[5280];   // [8 c][5 ky][132 xx]
    __shared__ float lw[1600];   // [25 tap][64 oc_local]
    int t = threadIdx.x;
    for (int i = t; i < 1600; i += 256) {
        int ol = i / 25, tap = i - ol * 25;
        lw[tap * 64 + ol] = wd[(cc * 64 + ol) * 25 + tap];
    }
    for (int i = t; i < 5280; i += 256) {
        int c = i / 660, rem = i - c * 660;
        int ky = rem / 132, xx = rem - ky * 132;
        int gy = y - 2 + ky, gx = xx - 2;
        float v = 0.f;
        if (gy >= 0 && gy < 128 && gx >= 0 && gx < 128)
            v = x[(((n * 32 + cc * 8 + c) * 128 + gy) << 7) + gx];
        lx[i] = v;
    }
    __syncthreads();
    int px = t >> 1, oh = t & 1;
    float acc[4][8];
#pragma unroll
    for (int j = 0; j < 4; ++j)
#pragma unroll
        for (int d = 0; d < 8; ++d) acc[j][d] = 0.f;
#pragma unroll
    for (int j = 0; j < 4; ++j) {
        int cl = oh * 4 + j;
        const float* lxc = &lx[cl * 660];
#pragma unroll
        for (int ky = 0; ky < 5; ++ky)
#pragma unroll
            for (int kx = 0; kx < 5; ++kx) {
                float xv = lxc[ky * 132 + px + kx];
                const float* w8 = &lw[(ky * 5 + kx) * 64 + cl * 8];
#pragma unroll
                for (int d = 0; d < 8; ++d) acc[j][d] += xv * w8[d];
            }
    }
    long base = ((long)((n * 128 + y) * 128 + px)) * 256 + cc * 64 + oh * 32;
#pragma unroll
    for (int j = 0; j < 4; ++j) {
        uint4 o;
        o.x = (u32)f2bf(acc[j][0]) | ((u32)f2bf(acc[j][1]) << 16);
        o.y = (u32)f2bf(acc[j][2]) | ((u32)f2bf(acc[j][3]) << 16);
        o.z = (u32)f2bf(acc[j][4]) | ((u32)f2bf(acc[j][5]) << 16);
        o.w = (u32)f2bf(acc[j][6]) | ((u32)f2bf(acc[j][7]) << 16);
        *(uint4*)(coeffs + base + j * 8) = o;
    }
}

// ---------------------------------------------------------------------------
// Repack conv weights OIHW f32 -> 32x32x16 B-fragment-order bf16:
// wp[((((tap*KC+kc)*2+s)*OC+oc)*2+h)*8 + j] = w[oc][kc*32+s*16+h*8+j][tap]
// ---------------------------------------------------------------------------
__global__ __launch_bounds__(256) void repack_w_k(const float* __restrict__ w,
                                                  u16* __restrict__ wp,
                                                  int OC, int IC, int total) {
    int f = blockIdx.x * 256 + threadIdx.x;
    if (f >= total) return;
    int KC = IC >> 5;
    int j  = f & 7;
    int h  = (f >> 3) & 1;
    int g  = f >> 4;           // ((tap*KC+kc)*2+s)*OC + oc
    int oc = g % OC; g /= OC;
    int s  = g & 1;  g >>= 1;  // tap*KC + kc
    int kc = g % KC;
    int tap = g / KC;
    int ic = kc * 32 + s * 16 + h * 8 + j;
    wp[f] = f2bf(w[(oc * IC + ic) * 9 + tap]);
}

// ---------------------------------------------------------------------------
// 3x3 conv, NHWC bf16 in/out, implicit GEMM with mfma_f32_32x32x16_bf16.
// Block: 128 px (one image row) x 256 oc; 4 waves (256 thr), each wave
// 128px x 64oc (acc[4][2] = 128 regs) -> B bytes/MFMA = 256 (R_B = 4),
// zero intra-block B duplication. 2 waves/SIMD (launch_bounds(256,2)).
// A: double-buffered LDS via global_load_lds (2-phase pipeline).
// B: self-overwriting 48-reg buffer, each subk issues its slot's next-dy
// load right after its MFMAs -> ~5-subk (~320 cyc) prefetch lead.
// ---------------------------------------------------------------------------
template<int IC, int OC>
__global__ __launch_bounds__(256, 2) void conv3_k(const u16* __restrict__ base,
                                                  u32 in_off,
                                                  const u16* __restrict__ wp,
                                                  const float* __restrict__ bias,
                                                  u32 zp_off,
                                                  u16* __restrict__ outp) {
    constexpr int KC = IC / 32;
    constexpr int W  = 130;             // 128 px + halo
    constexpr int TU = 12 * W;          // 1560 16B staging units per buffer
    constexpr int NFULL = TU / 256;     // 6
    constexpr int REM   = TU % 256;     // 24
    __shared__ u16 lA0[TU * 8];
    __shared__ u16 lA1[TU * 8];

    int bx = blockIdx.x;
    int y = bx & 127, n = bx >> 7;
    int ocb = blockIdx.y;
    int t = threadIdx.x, lane = t & 63, wv = t >> 6;
    int lm = lane & 31, h = lane >> 5;
    int ocw = ocb * 256 + wv * 64;

    // per-lane staging source offsets (u16 units from `base`)
    u32 off[NFULL + 1];
#pragma unroll
    for (int i = 0; i <= NFULL; ++i) {
        int u = (i == NFULL) ? (NFULL * 256 + lane) : (i * 256 + t);
        int icq = u / (3 * W);
        int r2  = u - icq * (3 * W);
        int dy  = r2 / W;
        int xx  = r2 - dy * W;
        int gy = y - 1 + dy, gx = xx - 1;
        bool ok = ((unsigned)gy < 128u) && ((unsigned)gx < 128u);
        off[i] = ok ? (in_off + (u32)((n * 128 + gy) * 128 + gx) * IC + (icq & 3) * 8)
                    : zp_off;
    }

    auto stage = [&](u16* dst, int kc) {
#pragma unroll
        for (int i = 0; i < NFULL; ++i)
            gl16(base + off[i] + kc * 32, dst + (i * 256 + wv * 64) * 8);
        if (wv == 0 && lane < REM)
            gl16(base + off[NFULL] + kc * 32, dst + NFULL * 256 * 8);
    };

    // B register buffer: 6 subk slots x 2 oc-frags
    bf16x8 B[6][2];
    u32 wboff = (u32)(ocw + lm) * 16 + h * 8;
#pragma unroll
    for (int dx = 0; dx < 3; ++dx)
#pragma unroll
        for (int s = 0; s < 2; ++s) {
            u32 wo = wboff + (u32)((dx * KC) * 2 + s) * (OC * 16);  // dy=0, kc=0
            B[dx * 2 + s][0] = *(const bf16x8*)(wp + wo);
            B[dx * 2 + s][1] = *(const bf16x8*)(wp + wo + 512);
        }

    f32x16 acc[4][2];
#pragma unroll
    for (int mf = 0; mf < 4; ++mf)
#pragma unroll
        for (int nf = 0; nf < 2; ++nf)
#pragma unroll
            for (int r = 0; r < 16; ++r) acc[mf][nf][r] = 0.f;

    // use B for (dyU) against lAu; refill each slot with (dyN, kcN)
    auto compDy = [&](const u16* lAu, int dyU, int dyN, int kcN) {
#pragma unroll
        for (int dx = 0; dx < 3; ++dx)
#pragma unroll
            for (int s = 0; s < 2; ++s) {
                int i = dx * 2 + s;
                int au = (((s * 2 + h) * 3 + dyU) * W + dx + lm) * 8;
                bf16x8 a0 = *(const bf16x8*)(lAu + au);
                bf16x8 a1 = *(const bf16x8*)(lAu + au + 256);
                bf16x8 a2 = *(const bf16x8*)(lAu + au + 512);
                bf16x8 a3 = *(const bf16x8*)(lAu + au + 768);
                __builtin_amdgcn_s_setprio(1);
                acc[0][0] = __builtin_amdgcn_mfma_f32_32x32x16_bf16(a0, B[i][0], acc[0][0], 0, 0, 0);
                acc[0][1] = __builtin_amdgcn_mfma_f32_32x32x16_bf16(a0, B[i][1], acc[0][1], 0, 0, 0);
                acc[1][0] = __builtin_amdgcn_mfma_f32_32x32x16_bf16(a1, B[i][0], acc[1][0], 0, 0, 0);
                acc[1][1] = __builtin_amdgcn_mfma_f32_32x32x16_bf16(a1, B[i][1], acc[1][1], 0, 0, 0);
                acc[2][0] = __builtin_amdgcn_mfma_f32_32x32x16_bf16(a2, B[i][0], acc[2][0], 0, 0, 0);
                acc[2][1] = __builtin_amdgcn_mfma_f32_32x32x16_bf16(a2, B[i][1], acc[2][1], 0, 0, 0);
                acc[3][0] = __builtin_amdgcn_mfma_f32_32x32x16_bf16(a3, B[i][0], acc[3][0], 0, 0, 0);
                acc[3][1] = __builtin_amdgcn_mfma_f32_32x32x16_bf16(a3, B[i][1], acc[3][1], 0, 0, 0);
                __builtin_amdgcn_s_setprio(0);
                u32 wo = wboff + (u32)(((dyN * 3 + dx) * KC + kcN) * 2 + s) * (OC * 16);
                B[i][0] = *(const bf16x8*)(wp + wo);
                B[i][1] = *(const bf16x8*)(wp + wo + 512);
            }
    };

    stage(lA0, 0);
    for (int kc = 0; kc < KC; kc += 2) {
        __syncthreads();                 // lA0 ready
        stage(lA1, kc + 1);
        compDy(lA0, 0, 1, kc);
        compDy(lA0, 1, 2, kc);
        compDy(lA0, 2, 0, kc + 1);
        __syncthreads();                 // lA1 ready
        if (kc + 2 < KC) stage(lA0, kc + 2);
        compDy(lA1, 0, 1, kc + 1);
        compDy(lA1, 1, 2, kc + 1);
        compDy(lA1, 2, 0, (kc + 2 < KC) ? kc + 2 : 0);
    }

    long rowb = (long)(n * 128 + y) * 128;
#pragma unroll
    for (int mf = 0; mf < 4; ++mf)
#pragma unroll
        for (int nf = 0; nf < 2; ++nf) {
            int oc = ocw + nf * 32 + lm;
            float bi = bias[oc];
#pragma unroll
            for (int r = 0; r < 16; ++r) {
                int px = mf * 32 + (r & 3) + ((r >> 2) << 3) + (h << 2);
                outp[(rowb + px) * OC + oc] = f2bf(acc[mf][nf][r] + bi);
            }
        }
}

// ---------------------------------------------------------------------------
// BN stats, stage 1: per-block partial (sum, sumsq) per channel over 1024 rows.
// ---------------------------------------------------------------------------
template<int C>
__global__ __launch_bounds__(256) void stats1_k(const u16* __restrict__ h,
                                                float* __restrict__ part) {
    constexpr int CH2 = C / 2;
    constexpr int PARTS = 256 / CH2;
    constexpr int RPB = 1024;
    constexpr int RPT = RPB / PARTS;
    int t = threadIdx.x;
    int chp = t % CH2, rp = t / CH2;
    long row0 = (long)blockIdx.x * RPB + (long)rp * RPT;
    float s0 = 0.f, q0 = 0.f, s1 = 0.f, q1 = 0.f;
    const u16* base = h + row0 * C + chp * 2;
    for (int r = 0; r < RPT; ++r) {
        u32 v = *(const u32*)(base + (long)r * C);
        float a = bf2f((u16)(v & 0xffff));
        float b = bf2f((u16)(v >> 16));
        s0 += a; q0 += a * a; s1 += b; q1 += b * b;
    }
    float4 o = make_float4(s0, q0, s1, q1);
    *(float4*)(part + ((long)(blockIdx.x * PARTS + rp) * CH2 + chp) * 4) = o;
}

template<int C>
__global__ __launch_bounds__(256) void stats2_k(const float* __restrict__ part,
                                                const float* __restrict__ g,
                                                const float* __restrict__ be,
                                                float* __restrict__ ab) {
    constexpr int CH2 = C / 2;
    constexpr int NP = 128 * (256 / CH2);
    int ch = blockIdx.x * 256 + threadIdx.x;
    if (ch >= C) return;
    int chp = ch >> 1, lo = ch & 1;
    float s = 0.f, q = 0.f;
    for (int p = 0; p < NP; ++p) {
        s += part[((long)p * CH2 + chp) * 4 + lo * 2];
        q += part[((long)p * CH2 + chp) * 4 + lo * 2 + 1];
    }
    const float M = 131072.f;
    float mean = s / M;
    float var = q / M - mean * mean;
    float a = g[ch] * rsqrtf(var + 1e-5f);
    ab[ch * 2]     = a;
    ab[ch * 2 + 1] = be[ch] - mean * a;
}

__global__ __launch_bounds__(256) void bn_relu_k(u16* __restrict__ h,
                                                 const float* __restrict__ ab) {
    long idx8 = (long)blockIdx.x * 256 + threadIdx.x;
    u16* p = h + idx8 * 8;
    uint4 v = *(const uint4*)p;
    int chb = ((int)idx8 & 63) << 3;
    u32 w[4] = {v.x, v.y, v.z, v.w};
    u32 o[4];
#pragma unroll
    for (int q = 0; q < 4; ++q) {
        int ch = chb + q * 2;
        float2 a0 = *(const float2*)(ab + ch * 2);
        float2 a1 = *(const float2*)(ab + ch * 2 + 2);
        float f0 = bf2f((u16)(w[q] & 0xffff));
        float f1 = bf2f((u16)(w[q] >> 16));
        f0 = fmaxf(f0 * a0.x + a0.y, 0.f);
        f1 = fmaxf(f1 * a1.x + a1.y, 0.f);
        o[q] = (u32)f2bf(f0) | ((u32)f2bf(f1) << 16);
    }
    *(uint4*)p = make_uint4(o[0], o[1], o[2], o[3]);
}

__global__ __launch_bounds__(256) void inv_conv_k(const u16* __restrict__ h2,
                                                  const float* __restrict__ ab,
                                                  const float* __restrict__ winv,
                                                  const float* __restrict__ binv,
                                                  float* __restrict__ out) {
    __shared__ float lw[8192];   // [256 k][32 oc]
    __shared__ float lab[512];
    int t = threadIdx.x;
    for (int i = t; i < 8192; i += 256) {
        int k = i >> 5, oc = i & 31;
        lw[i] = winv[oc * 256 + k];
    }
    lab[t] = ab[t];
    lab[t + 256] = ab[t + 256];
    __syncthreads();
    long p = (long)blockIdx.x * 256 + t;
    const u16* hp = h2 + p * 256;
    f32x4 acc[8];
    f32x4 zero = {0.f, 0.f, 0.f, 0.f};
#pragma unroll
    for (int q = 0; q < 8; ++q) acc[q] = zero;
    for (int k = 0; k < 256; k += 8) {
        uint4 hv = *(const uint4*)(hp + k);
        u32 wv[4] = {hv.x, hv.y, hv.z, hv.w};
#pragma unroll
        for (int e = 0; e < 8; ++e) {
            u16 us = (e & 1) ? (u16)(wv[e >> 1] >> 16) : (u16)(wv[e >> 1] & 0xffff);
            int kk = k + e;
            float v = bf2f(us);
            v = fmaxf(v * lab[kk * 2] + lab[kk * 2 + 1], 0.f);
            const f32x4* w4 = (const f32x4*)(lw + kk * 32);
#pragma unroll
            for (int q = 0; q < 8; ++q) acc[q] += v * w4[q];
        }
    }
    int n = (int)(p >> 14), rem = (int)(p & 16383);
#pragma unroll
    for (int q = 0; q < 8; ++q)
#pragma unroll
        for (int c = 0; c < 4; ++c) {
            int oc = q * 4 + c;
            out[((long)(n * 32 + oc) << 14) + rem] = acc[q][c] + binv[oc];
        }
}

// ---------------------------------------------------------------------------
// Workspace layout (bytes) — ~200 MiB:
//   0         w1p   (2,359,296)
//   2359296   w2p   (2,359,296)
//   4718592   part  (524,288)
//   5242880   ab1   (4,096)
//   5246976   ab2   (2,048)
//   5249024   zp    (1,024)  zero page for conv halo
//   8388608   coeffs / h2 (67,108,864)
//   75497472  h1    (134,217,728)
// ---------------------------------------------------------------------------
extern "C" void kernel_launch(void* const* d_in, const int* in_sizes, int n_in,
                              void* d_out, int out_size, void* d_ws, size_t ws_size,
                              hipStream_t stream) {
    const float* x     = (const float*)d_in[0];
    const float* w_dir = (const float*)d_in[1];
    const float* w1    = (const float*)d_in[2];
    const float* b1    = (const float*)d_in[3];
    const float* g1    = (const float*)d_in[4];
    const float* be1   = (const float*)d_in[5];
    const float* w2    = (const float*)d_in[6];
    const float* b2    = (const float*)d_in[7];
    const float* g2    = (const float*)d_in[8];
    const float* be2   = (const float*)d_in[9];
    const float* w_inv = (const float*)d_in[10];
    const float* b_inv = (const float*)d_in[11];
    float* out = (float*)d_out;
    char* ws = (char*)d_ws;

    u16*   w1p  = (u16*)(ws + 0);
    u16*   w2p  = (u16*)(ws + 2359296);
    float* part = (float*)(ws + 4718592);
    float* ab1  = (float*)(ws + 5242880);
    float* ab2  = (float*)(ws + 5246976);
    u16*   zp   = (u16*)(ws + 5249024);
    u16*   coef = (u16*)(ws + 8388608);     // also h2
    u16*   h1   = (u16*)(ws + 75497472);
    const u16* basep = (const u16*)ws;
    u32 zp_off   = 5249024 / 2;
    u32 coef_off = 8388608 / 2;
    u32 h1_off   = 75497472 / 2;

    hipMemsetAsync(zp, 0, 1024, stream);
    repack_w_k<<<4608, 256, 0, stream>>>(w1, w1p, 512, 256, 1179648);
    repack_w_k<<<4608, 256, 0, stream>>>(w2, w2p, 256, 512, 1179648);
    dir_conv_k<<<4096, 256, 0, stream>>>(x, w_dir, coef);
    conv3_k<256, 512><<<dim3(1024, 2), 256, 0, stream>>>(basep, coef_off, w1p, b1, zp_off, h1);
    stats1_k<512><<<128, 256, 0, stream>>>(h1, part);
    stats2_k<512><<<2, 256, 0, stream>>>(part, g1, be1, ab1);
    bn_relu_k<<<32768, 256, 0, stream>>>(h1, ab1);
    conv3_k<512, 256><<<dim3(1024, 1), 256, 0, stream>>>(basep, h1_off, w2p, b2, zp_off, coef);
    stats1_k<256><<<128, 256, 0, stream>>>(coef, part);
    stats2_k<256><<<1, 256, 0, stream>>>(part, g2, be2, ab2);
    inv_conv_k<<<512, 256, 0, stream>>>(coef, ab2, w_inv, b_inv, out);
}

// Round 7
// 729.660 us; speedup vs baseline: 1.8769x; 1.1254x over previous
//
#include <hip/hip_runtime.h>

typedef unsigned short u16;
typedef unsigned int   u32;
typedef __attribute__((ext_vector_type(8)))  __bf16 bf16x8;
typedef __attribute__((ext_vector_type(4)))  float  f32x4;
typedef __attribute__((ext_vector_type(16))) float  f32x16;

__device__ __forceinline__ float bf2f(u16 u) {
    union { u32 i; float f; } v; v.i = ((u32)u) << 16; return v.f;
}
__device__ __forceinline__ u16 f2bf(float f) {
    u32 u = __float_as_uint(f);
    u32 r = (u + 0x7FFFu + ((u >> 16) & 1u)) >> 16;
    return (u16)r;
}

__device__ __forceinline__ void gl16(const u16* g, u16* l) {
    __builtin_amdgcn_global_load_lds(
        (const __attribute__((address_space(1))) unsigned int*)g,
        (__attribute__((address_space(3))) unsigned int*)l, 16, 0, 0);
}

// ---------------------------------------------------------------------------
// Kernel 1: grouped directional conv 5x5, C=32 -> 256, pad=2, no bias.
// ---------------------------------------------------------------------------
__global__ __launch_bounds__(256) void dir_conv_k(const float* __restrict__ x,
                                                  const float* __restrict__ wd,
                                                  u16* __restrict__ coeffs) {
    int bid = blockIdx.x;
    int cc = bid & 3, y = (bid >> 2) & 127, n = bid >> 9;
    __shared__ float lx[5280];   // [8 c][5 ky][132 xx]
    __shared__ float lw[1600];   // [25 tap][64 oc_local]
    int t = threadIdx.x;
    for (int i = t; i < 1600; i += 256) {
        int ol = i / 25, tap = i - ol * 25;
        lw[tap * 64 + ol] = wd[(cc * 64 + ol) * 25 + tap];
    }
    for (int i = t; i < 5280; i += 256) {
        int c = i / 660, rem = i - c * 660;
        int ky = rem / 132, xx = rem - ky * 132;
        int gy = y - 2 + ky, gx = xx - 2;
        float v = 0.f;
        if (gy >= 0 && gy < 128 && gx >= 0 && gx < 128)
            v = x[(((n * 32 + cc * 8 + c) * 128 + gy) << 7) + gx];
        lx[i] = v;
    }
    __syncthreads();
    int px = t >> 1, oh = t & 1;
    float acc[4][8];
#pragma unroll
    for (int j = 0; j < 4; ++j)
#pragma unroll
        for (int d = 0; d < 8; ++d) acc[j][d] = 0.f;
#pragma unroll
    for (int j = 0; j < 4; ++j) {
        int cl = oh * 4 + j;
        const float* lxc = &lx[cl * 660];
#pragma unroll
        for (int ky = 0; ky < 5; ++ky)
#pragma unroll
            for (int kx = 0; kx < 5; ++kx) {
                float xv = lxc[ky * 132 + px + kx];
                const float* w8 = &lw[(ky * 5 + kx) * 64 + cl * 8];
#pragma unroll
                for (int d = 0; d < 8; ++d) acc[j][d] += xv * w8[d];
            }
    }
    long base = ((long)((n * 128 + y) * 128 + px)) * 256 + cc * 64 + oh * 32;
#pragma unroll
    for (int j = 0; j < 4; ++j) {
        uint4 o;
        o.x = (u32)f2bf(acc[j][0]) | ((u32)f2bf(acc[j][1]) << 16);
        o.y = (u32)f2bf(acc[j][2]) | ((u32)f2bf(acc[j][3]) << 16);
        o.z = (u32)f2bf(acc[j][4]) | ((u32)f2bf(acc[j][5]) << 16);
        o.w = (u32)f2bf(acc[j][6]) | ((u32)f2bf(acc[j][7]) << 16);
        *(uint4*)(coeffs + base + j * 8) = o;
    }
}

// ---------------------------------------------------------------------------
// Repack conv weights OIHW f32 -> 32x32x16 B-fragment-order bf16:
// wp[((((tap*KC+kc)*2+s)*OC+oc)*2+h)*8 + j] = w[oc][kc*32+s*16+h*8+j][tap]
// ---------------------------------------------------------------------------
__global__ __launch_bounds__(256) void repack_w_k(const float* __restrict__ w,
                                                  u16* __restrict__ wp,
                                                  int OC, int IC, int total) {
    int f = blockIdx.x * 256 + threadIdx.x;
    if (f >= total) return;
    int KC = IC >> 5;
    int j  = f & 7;
    int h  = (f >> 3) & 1;
    int g  = f >> 4;           // ((tap*KC+kc)*2+s)*OC + oc
    int oc = g % OC; g /= OC;
    int s  = g & 1;  g >>= 1;  // tap*KC + kc
    int kc = g % KC;
    int tap = g / KC;
    int ic = kc * 32 + s * 16 + h * 8 + j;
    wp[f] = f2bf(w[(oc * IC + ic) * 9 + tap]);
}

// ---------------------------------------------------------------------------
// 3x3 conv, NHWC bf16 in/out, implicit GEMM with mfma_f32_32x32x16_bf16.
// Block: 128 px (one image row) x 256 oc; 4 waves, wave tile 128px x 64oc
// (acc[4][2]); 2 waves/SIMD. A: dbuf LDS via global_load_lds, 1 barrier/kc.
// Inner loop: explicit 1-subk-deep ping-pong pipeline (Ar/Br[2]) so the
// compiler emits counted lgkmcnt waits (ds_reads of subk i+1 in flight
// during subk i's MFMAs). setprio around MFMA cluster. XCD-swizzled bx.
// Fused BN-stats partials (atomicAdd into statp, pre-zeroed).
// ---------------------------------------------------------------------------
template<int IC, int OC>
__global__ __launch_bounds__(256, 2) void conv3_k(const u16* __restrict__ base,
                                                  u32 in_off,
                                                  const u16* __restrict__ wp,
                                                  const float* __restrict__ bias,
                                                  u32 zp_off,
                                                  u16* __restrict__ outp,
                                                  float* __restrict__ statp) {
    constexpr int KC = IC / 32;
    constexpr int W  = 130;             // 128 px + halo
    constexpr int TU = 12 * W;          // 1560 16B staging units per buffer
    constexpr int NFULL = TU / 256;     // 6
    constexpr int REM   = TU % 256;     // 24
    __shared__ u16 lA0[TU * 8];
    __shared__ u16 lA1[TU * 8];

    int bx0 = blockIdx.x;
    int bx = ((bx0 & 7) << 7) + (bx0 >> 3);   // XCD swizzle (1024 % 8 == 0)
    int y = bx & 127, n = bx >> 7;
    int ocb = blockIdx.y;
    int t = threadIdx.x, lane = t & 63, wv = t >> 6;
    int lm = lane & 31, h = lane >> 5;
    int ocw = ocb * 256 + wv * 64;

    // per-lane staging source offsets (u16 units from `base`)
    u32 off[NFULL + 1];
#pragma unroll
    for (int i = 0; i <= NFULL; ++i) {
        int u = (i == NFULL) ? (NFULL * 256 + lane) : (i * 256 + t);
        int icq = u / (3 * W);
        int r2  = u - icq * (3 * W);
        int dy  = r2 / W;
        int xx  = r2 - dy * W;
        int gy = y - 1 + dy, gx = xx - 1;
        bool ok = ((unsigned)gy < 128u) && ((unsigned)gx < 128u);
        off[i] = ok ? (in_off + (u32)((n * 128 + gy) * 128 + gx) * IC + (icq & 3) * 8)
                    : zp_off;
    }

    auto stage = [&](u16* dst, int kc) {
#pragma unroll
        for (int i = 0; i < NFULL; ++i)
            gl16(base + off[i] + kc * 32, dst + (i * 256 + wv * 64) * 8);
        if (wv == 0 && lane < REM)
            gl16(base + off[NFULL] + kc * 32, dst + NFULL * 256 * 8);
    };

    u32 wboff = (u32)(ocw + lm) * 16 + h * 8;
    bf16x8 Ar[2][4];
    bf16x8 Br[2][2];

    // initial B for (dy=0,dx=0,s=0,kc=0)
    {
        const u16* wb = wp + wboff;
        Br[0][0] = *(const bf16x8*)wb;
        Br[0][1] = *(const bf16x8*)(wb + 512);
    }

    f32x16 acc[4][2];
#pragma unroll
    for (int mf = 0; mf < 4; ++mf)
#pragma unroll
        for (int nf = 0; nf < 2; ++nf)
#pragma unroll
            for (int r = 0; r < 16; ++r) acc[mf][nf][r] = 0.f;

    stage(lA0, 0);
    for (int kc = 0; kc < KC; ++kc) {
        const u16* lAu = (kc & 1) ? lA1 : lA0;
        u16*       lAn = (kc & 1) ? lA0 : lA1;
        __syncthreads();                 // lAu staged; lAn free to overwrite
        // A reads for subk0 (s=0,dy=0,dx=0) — critical path first
        {
            int au = ((h * 3) * W + lm) * 8;
            Ar[0][0] = *(const bf16x8*)(lAu + au);
            Ar[0][1] = *(const bf16x8*)(lAu + au + 256);
            Ar[0][2] = *(const bf16x8*)(lAu + au + 512);
            Ar[0][3] = *(const bf16x8*)(lAu + au + 768);
        }
        if (kc + 1 < KC) stage(lAn, kc + 1);
#pragma unroll
        for (int i = 0; i < 18; ++i) {
            const int j   = (i + 1) % 18;
            const int jdy = j / 6, jdx = (j % 6) >> 1, js = j & 1;
            const int jkc = (i == 17) ? ((kc + 1 < KC) ? kc + 1 : 0) : kc;
            if (i != 17) {               // A prefetch (not across barrier)
                int au = (((js * 2 + h) * 3 + jdy) * W + jdx + lm) * 8;
                Ar[j & 1][0] = *(const bf16x8*)(lAu + au);
                Ar[j & 1][1] = *(const bf16x8*)(lAu + au + 256);
                Ar[j & 1][2] = *(const bf16x8*)(lAu + au + 512);
                Ar[j & 1][3] = *(const bf16x8*)(lAu + au + 768);
            }
            {                            // B prefetch (wraps into next kc)
                const u16* wb = wp + wboff
                    + (u32)(((jdy * 3 + jdx) * KC + jkc) * 2 + js) * (OC * 16);
                Br[j & 1][0] = *(const bf16x8*)wb;
                Br[j & 1][1] = *(const bf16x8*)(wb + 512);
            }
            __builtin_amdgcn_s_setprio(1);
            acc[0][0] = __builtin_amdgcn_mfma_f32_32x32x16_bf16(Ar[i & 1][0], Br[i & 1][0], acc[0][0], 0, 0, 0);
            acc[0][1] = __builtin_amdgcn_mfma_f32_32x32x16_bf16(Ar[i & 1][0], Br[i & 1][1], acc[0][1], 0, 0, 0);
            acc[1][0] = __builtin_amdgcn_mfma_f32_32x32x16_bf16(Ar[i & 1][1], Br[i & 1][0], acc[1][0], 0, 0, 0);
            acc[1][1] = __builtin_amdgcn_mfma_f32_32x32x16_bf16(Ar[i & 1][1], Br[i & 1][1], acc[1][1], 0, 0, 0);
            acc[2][0] = __builtin_amdgcn_mfma_f32_32x32x16_bf16(Ar[i & 1][2], Br[i & 1][0], acc[2][0], 0, 0, 0);
            acc[2][1] = __builtin_amdgcn_mfma_f32_32x32x16_bf16(Ar[i & 1][2], Br[i & 1][1], acc[2][1], 0, 0, 0);
            acc[3][0] = __builtin_amdgcn_mfma_f32_32x32x16_bf16(Ar[i & 1][3], Br[i & 1][0], acc[3][0], 0, 0, 0);
            acc[3][1] = __builtin_amdgcn_mfma_f32_32x32x16_bf16(Ar[i & 1][3], Br[i & 1][1], acc[3][1], 0, 0, 0);
            __builtin_amdgcn_s_setprio(0);
        }
    }

    long rowb = (long)(n * 128 + y) * 128;
    float ss[2] = {0.f, 0.f}, qq[2] = {0.f, 0.f};
#pragma unroll
    for (int nf = 0; nf < 2; ++nf) {
        int oc = ocw + nf * 32 + lm;
        float bi = bias[oc];
#pragma unroll
        for (int mf = 0; mf < 4; ++mf)
#pragma unroll
            for (int r = 0; r < 16; ++r) {
                int px = mf * 32 + (r & 3) + ((r >> 2) << 3) + (h << 2);
                u16 bv = f2bf(acc[mf][nf][r] + bi);
                outp[(rowb + px) * OC + oc] = bv;
                float vr = bf2f(bv);
                ss[nf] += vr;
                qq[nf] += vr * vr;
            }
    }
#pragma unroll
    for (int nf = 0; nf < 2; ++nf) {
        ss[nf] += __shfl_xor(ss[nf], 32);
        qq[nf] += __shfl_xor(qq[nf], 32);
    }
    if (h == 0) {
#pragma unroll
        for (int nf = 0; nf < 2; ++nf) {
            int oc = ocw + nf * 32 + lm;
            atomicAdd(&statp[oc * 2],     ss[nf]);
            atomicAdd(&statp[oc * 2 + 1], qq[nf]);
        }
    }
}

// Stage 2: per-channel affine (a, b): a*x+b == BN(x), from fused partials.
template<int C>
__global__ __launch_bounds__(256) void stats2_k(const float* __restrict__ part,
                                                const float* __restrict__ g,
                                                const float* __restrict__ be,
                                                float* __restrict__ ab) {
    int ch = blockIdx.x * 256 + threadIdx.x;
    if (ch >= C) return;
    float s = part[ch * 2], q = part[ch * 2 + 1];
    const float M = 131072.f;
    float mean = s / M;
    float var = q / M - mean * mean;
    float a = g[ch] * rsqrtf(var + 1e-5f);
    ab[ch * 2]     = a;
    ab[ch * 2 + 1] = be[ch] - mean * a;
}

__global__ __launch_bounds__(256) void bn_relu_k(u16* __restrict__ h,
                                                 const float* __restrict__ ab) {
    long idx8 = (long)blockIdx.x * 256 + threadIdx.x;
    u16* p = h + idx8 * 8;
    uint4 v = *(const uint4*)p;
    int chb = ((int)idx8 & 63) << 3;
    u32 w[4] = {v.x, v.y, v.z, v.w};
    u32 o[4];
#pragma unroll
    for (int q = 0; q < 4; ++q) {
        int ch = chb + q * 2;
        float2 a0 = *(const float2*)(ab + ch * 2);
        float2 a1 = *(const float2*)(ab + ch * 2 + 2);
        float f0 = bf2f((u16)(w[q] & 0xffff));
        float f1 = bf2f((u16)(w[q] >> 16));
        f0 = fmaxf(f0 * a0.x + a0.y, 0.f);
        f1 = fmaxf(f1 * a1.x + a1.y, 0.f);
        o[q] = (u32)f2bf(f0) | ((u32)f2bf(f1) << 16);
    }
    *(uint4*)p = make_uint4(o[0], o[1], o[2], o[3]);
}

__global__ __launch_bounds__(256) void inv_conv_k(const u16* __restrict__ h2,
                                                  const float* __restrict__ ab,
                                                  const float* __restrict__ winv,
                                                  const float* __restrict__ binv,
                                                  float* __restrict__ out) {
    __shared__ float lw[8192];   // [256 k][32 oc]
    __shared__ float lab[512];
    int t = threadIdx.x;
    for (int i = t; i < 8192; i += 256) {
        int k = i >> 5, oc = i & 31;
        lw[i] = winv[oc * 256 + k];
    }
    lab[t] = ab[t];
    lab[t + 256] = ab[t + 256];
    __syncthreads();
    long p = (long)blockIdx.x * 256 + t;
    const u16* hp = h2 + p * 256;
    f32x4 acc[8];
    f32x4 zero = {0.f, 0.f, 0.f, 0.f};
#pragma unroll
    for (int q = 0; q < 8; ++q) acc[q] = zero;
    for (int k = 0; k < 256; k += 8) {
        uint4 hv = *(const uint4*)(hp + k);
        u32 wv[4] = {hv.x, hv.y, hv.z, hv.w};
#pragma unroll
        for (int e = 0; e < 8; ++e) {
            u16 us = (e & 1) ? (u16)(wv[e >> 1] >> 16) : (u16)(wv[e >> 1] & 0xffff);
            int kk = k + e;
            float v = bf2f(us);
            v = fmaxf(v * lab[kk * 2] + lab[kk * 2 + 1], 0.f);
            const f32x4* w4 = (const f32x4*)(lw + kk * 32);
#pragma unroll
            for (int q = 0; q < 8; ++q) acc[q] += v * w4[q];
        }
    }
    int n = (int)(p >> 14), rem = (int)(p & 16383);
#pragma unroll
    for (int q = 0; q < 8; ++q)
#pragma unroll
        for (int c = 0; c < 4; ++c) {
            int oc = q * 4 + c;
            out[((long)(n * 32 + oc) << 14) + rem] = acc[q][c] + binv[oc];
        }
}

// ---------------------------------------------------------------------------
// Workspace layout (bytes) — ~200 MiB:
//   0         w1p   (2,359,296)
//   2359296   w2p   (2,359,296)
//   4718592   part1 (4,096)  fused BN1 stats (s,q per oc)
//   4722688   part2 (2,048)  fused BN2 stats
//   5242880   ab1   (4,096)
//   5246976   ab2   (2,048)
//   5249024   zp    (1,024)  zero page for conv halo
//   8388608   coeffs / h2 (67,108,864)
//   75497472  h1    (134,217,728)
// ---------------------------------------------------------------------------
extern "C" void kernel_launch(void* const* d_in, const int* in_sizes, int n_in,
                              void* d_out, int out_size, void* d_ws, size_t ws_size,
                              hipStream_t stream) {
    const float* x     = (const float*)d_in[0];
    const float* w_dir = (const float*)d_in[1];
    const float* w1    = (const float*)d_in[2];
    const float* b1    = (const float*)d_in[3];
    const float* g1    = (const float*)d_in[4];
    const float* be1   = (const float*)d_in[5];
    const float* w2    = (const float*)d_in[6];
    const float* b2    = (const float*)d_in[7];
    const float* g2    = (const float*)d_in[8];
    const float* be2   = (const float*)d_in[9];
    const float* w_inv = (const float*)d_in[10];
    const float* b_inv = (const float*)d_in[11];
    float* out = (float*)d_out;
    char* ws = (char*)d_ws;

    u16*   w1p   = (u16*)(ws + 0);
    u16*   w2p   = (u16*)(ws + 2359296);
    float* part1 = (float*)(ws + 4718592);
    float* part2 = (float*)(ws + 4722688);
    float* ab1   = (float*)(ws + 5242880);
    float* ab2   = (float*)(ws + 5246976);
    u16*   zp    = (u16*)(ws + 5249024);
    u16*   coef  = (u16*)(ws + 8388608);     // also h2
    u16*   h1    = (u16*)(ws + 75497472);
    const u16* basep = (const u16*)ws;
    u32 zp_off   = 5249024 / 2;
    u32 coef_off = 8388608 / 2;
    u32 h1_off   = 75497472 / 2;

    hipMemsetAsync(zp, 0, 1024, stream);
    hipMemsetAsync(part1, 0, 8192, stream);   // covers part1 + part2
    repack_w_k<<<4608, 256, 0, stream>>>(w1, w1p, 512, 256, 1179648);
    repack_w_k<<<4608, 256, 0, stream>>>(w2, w2p, 256, 512, 1179648);
    dir_conv_k<<<4096, 256, 0, stream>>>(x, w_dir, coef);
    conv3_k<256, 512><<<dim3(1024, 2), 256, 0, stream>>>(basep, coef_off, w1p, b1, zp_off, h1, part1);
    stats2_k<512><<<2, 256, 0, stream>>>(part1, g1, be1, ab1);
    bn_relu_k<<<32768, 256, 0, stream>>>(h1, ab1);
    conv3_k<512, 256><<<dim3(1024, 1), 256, 0, stream>>>(basep, h1_off, w2p, b2, zp_off, coef, part2);
    stats2_k<256><<<1, 256, 0, stream>>>(part2, g2, be2, ab2);
    inv_conv_k<<<512, 256, 0, stream>>>(coef, ab2, w_inv, b_inv, out);
}